// Round 17
// baseline (427.189 us; speedup 1.0000x reference)
//
#include <hip/hip_runtime.h>

// 3D Jacobi (6-neighbor), 20 sweeps, zero-Dirichlet.
// step_first_v (padded pre -> ws + g=h^2*f) + 6x fused TRIPLE-sweeps
// (2.5D z-march, CZ=32 to amortize pipeline fill; x-PAIR threads,
// bank-permuted LDS columns, padded row stride, register rings,
// 1 barrier/iter) + 1 single float4 sweep.

#define NP 258
#define NI 256
#define HHC ((1.0f / 257.0f) * (1.0f / 257.0f))
#define SIXTH (1.0f / 6.0f)

#define TX 32
#define TY 32
#define CZ 32
#define NR 38    // region rows: gy in [y0-3, y0+35)
#define NC 10    // f4 x-chunks: gx in [x0-4, x0+36)
#define NCP 11   // padded LDS row stride (f4)

__device__ __forceinline__ float4 ld4u(const float* p) {
    float4 v; __builtin_memcpy(&v, p, sizeof(float4)); return v;
}
__device__ __forceinline__ float4 zero4() { return make_float4(0.f, 0.f, 0.f, 0.f); }
__device__ __forceinline__ float4 ldg4(const float* p) {
    return *reinterpret_cast<const float4*>(p);
}
__device__ __forceinline__ int permc(int c) { return (c & 1) * 5 + (c >> 1); }

// First sweep, vectorized: padded pre (incl. random halo) -> out, g = h^2*f.
__global__ void step_first_v(const float* __restrict__ pre,
                             const float* __restrict__ f,
                             float* __restrict__ out,
                             float* __restrict__ g) {
    const int tx = threadIdx.x;
    const int y  = blockIdx.y * 4 + threadIdx.y;
    const int z  = blockIdx.z;
    const int gx0 = 4 * tx;
    const size_t sP = (size_t)NP * NP;
    const size_t prow = (size_t)(z + 1) * sP + (size_t)(y + 1) * NP + 1;

    const float4 C  = ld4u(&pre[prow + gx0]);
    const float4 up = ld4u(&pre[prow - NP + gx0]);
    const float4 dn = ld4u(&pre[prow + NP + gx0]);
    const float4 zm = ld4u(&pre[prow - sP + gx0]);
    const float4 zp = ld4u(&pre[prow + sP + gx0]);
    float4 fv = ld4u(&f[prow + gx0]);
    fv.x *= HHC; fv.y *= HHC; fv.z *= HHC; fv.w *= HHC;

    float lft = __shfl_up(C.w, 1);
    if (tx == 0)  lft = pre[prow + gx0 - 1];
    float rgt = __shfl_down(C.x, 1);
    if (tx == 63) rgt = pre[prow + gx0 + 4];

    float4 o;
    o.x = (lft + C.y + up.x + dn.x + zm.x + zp.x + fv.x) * SIXTH;
    o.y = (C.x + C.z + up.y + dn.y + zm.y + zp.y + fv.y) * SIXTH;
    o.z = (C.y + C.w + up.z + dn.z + zm.z + zp.z + fv.z) * SIXTH;
    o.w = (C.z + rgt + up.w + dn.w + zm.w + zp.w + fv.w) * SIXTH;

    const size_t oi = ((size_t)z * NI + y) * NI + gx0;
    *reinterpret_cast<float4*>(&out[oi]) = o;
    *reinterpret_cast<float4*>(&g[oi])  = fv;
}

// Final single sweep, float4, using g.
__global__ void step_last_v(const float4* __restrict__ u4,
                            const float4* __restrict__ g4,
                            float4* __restrict__ out4) {
    const int tx = threadIdx.x;
    const int y  = blockIdx.y * 4 + threadIdx.y;
    const int z  = blockIdx.z;
    const int rowq   = NI / 4;
    const int planeq = NI * rowq;
    const int r = z * planeq + y * rowq + tx;

    const float4 v = u4[r];
    float left  = __shfl_up(v.w, 1);
    float right = __shfl_down(v.x, 1);
    if (tx == 0)  left  = 0.0f;
    if (tx == 63) right = 0.0f;

    float4 nb;
    nb.x = left + v.y;
    nb.y = v.x  + v.z;
    nb.z = v.y  + v.w;
    nb.w = v.z  + right;

    if (y > 0)      { float4 b = u4[r - rowq];   nb.x += b.x; nb.y += b.y; nb.z += b.z; nb.w += b.w; }
    if (y < NI - 1) { float4 b = u4[r + rowq];   nb.x += b.x; nb.y += b.y; nb.z += b.z; nb.w += b.w; }
    if (z > 0)      { float4 b = u4[r - planeq]; nb.x += b.x; nb.y += b.y; nb.z += b.z; nb.w += b.w; }
    if (z < NI - 1) { float4 b = u4[r + planeq]; nb.x += b.x; nb.y += b.y; nb.z += b.z; nb.w += b.w; }

    const float4 gv = g4[r];
    float4 o;
    o.x = (nb.x + gv.x) * SIXTH;
    o.y = (nb.y + gv.y) * SIXTH;
    o.z = (nb.z + gv.z) * SIXTH;
    o.w = (nb.w + gv.w) * SIXTH;
    out4[r] = o;
}

// Fused TRIPLE sweep out = J(J(J(u))), x-pair threads, permuted cols + padded rows.
__global__ __launch_bounds__(192, 3)
void step_fused3x(const float* __restrict__ u,
                  const float* __restrict__ g,
                  float* __restrict__ out) {
    __shared__ float4 su [2][NR][NCP];
    __shared__ float4 sw1[2][NR][NCP];
    __shared__ float4 sw2[2][NR][NCP];

    const int tid = threadIdx.x;

    // XCD-contiguous tile remap (grid 8x8x8 = 512 = 8 XCDs x 64).
    const int lid = blockIdx.x + (blockIdx.y << 3) + (blockIdx.z << 6);
    const int swzid = (lid & 7) * 64 + (lid >> 3);
    const int x0 = (swzid & 7) * TX;
    const int y0 = ((swzid >> 3) & 7) * TY;
    const int z0 = (swzid >> 6) * CZ;
    const int zend = z0 + CZ;
    const int plq = NI * NI;

    const int rp = tid / 5, xp = tid - rp * 5;
    const bool act = rp < NR;                        // tid < 190
    const int c0 = 2 * xp, c1 = c0 + 1;
    const int gy  = y0 - 3 + rp;
    const int gx0c = x0 - 4 + 4 * c0;
    const int gx1c = gx0c + 4;                       // = x0 + 8*xp
    const bool gyok = act && gy >= 0 && gy < NI;
    const bool in0 = gyok && gx0c >= 0 && gx0c < NI;
    const bool in1 = gyok && gx1c < NI;              // right-halo chunk of last tile is OOB
    const int base0 = gy * NI + gx0c;
    const int base1 = base0 + 4;

    // permuted LDS columns (even chunks -> 0..4, odd -> 5..9)
    const int pc0 = xp;                              // permc(c0)
    const int pc1 = 5 + xp;                          // permc(c1)
    const int pcm = permc((c0 > 0) ? c0 - 1 : 0);    // left neighbor of pair (clamped)
    const int pcp = permc((c1 < 9) ? c1 + 1 : 9);    // right neighbor of pair (clamped)

    const bool row_w1 = rp >= 1 && rp <= 36;
    const bool row_w2 = rp >= 2 && rp <= 35;
    const bool row_o  = act && rp >= 3 && rp <= 34;
    const bool w1ok0 = in0 && row_w1, w1ok1 = in1 && row_w1;
    const bool w2ok0 = in0 && row_w2, w2ok1 = in1 && row_w2;
    const bool ook0  = row_o && c0 >= 1 && c0 <= 8;  // xp>=1
    const bool ook1  = row_o && c1 <= 8;             // xp<=3

    // Register rings (per chunk) + prefetch
    float4 ru0 = zero4(), ru1 = zero4(), gn0 = zero4(), gn1 = zero4();
    float4 u_zm0 = zero4(), u_c0 = zero4(), u_zp0 = zero4();
    float4 u_zm1 = zero4(), u_c1 = zero4(), u_zp1 = zero4();
    float4 w1_zm0 = zero4(), w1_c0 = zero4(), w1_zp0 = zero4();
    float4 w1_zm1 = zero4(), w1_c1 = zero4(), w1_zp1 = zero4();
    float4 w2_zm0 = zero4(), w2_c0 = zero4(), w2_zp0 = zero4();
    float4 w2_zm1 = zero4(), w2_c1 = zero4(), w2_zp1 = zero4();
    float4 g0_0 = zero4(), g0_1 = zero4(), g1_0 = zero4(), g1_1 = zero4();
    float4 g2_0 = zero4(), g2_1 = zero4();

    // Prologue: u_zp <- u(z0-3), ru <- u(z0-2)  (zeros for planes < 0)
    if (z0 - 3 >= 0) {
        if (in0) u_zp0 = ldg4(&u[(size_t)(z0 - 3) * plq + base0]);
        if (in1) u_zp1 = ldg4(&u[(size_t)(z0 - 3) * plq + base1]);
    }
    if (z0 - 2 >= 0) {
        if (in0) ru0 = ldg4(&u[(size_t)(z0 - 2) * plq + base0]);
        if (in1) ru1 = ldg4(&u[(size_t)(z0 - 2) * plq + base1]);
    }

    for (int t = z0 - 5; t < zend; ++t) {
        // ---- stage: su plane t+3 (slot (t+3)&1); ring shifts; prefetch u(t+4), g(t+3) ----
        if (act) { su[(t + 3) & 1][rp][pc0] = ru0; su[(t + 3) & 1][rp][pc1] = ru1; }
        u_zm0 = u_c0; u_c0 = u_zp0; u_zp0 = ru0;
        u_zm1 = u_c1; u_c1 = u_zp1; u_zp1 = ru1;
        g0_0 = g1_0; g0_1 = g1_1; g1_0 = g2_0; g1_1 = g2_1; g2_0 = gn0; g2_1 = gn1;
        ru0 = zero4(); ru1 = zero4(); gn0 = zero4(); gn1 = zero4();
        if (t < zend - 1) {
            if (t + 4 >= 0 && t + 4 < NI) {
                if (in0) ru0 = ldg4(&u[(size_t)(t + 4) * plq + base0]);
                if (in1) ru1 = ldg4(&u[(size_t)(t + 4) * plq + base1]);
            }
            if (t + 3 >= 0 && t + 3 < NI) {
                if (in0) gn0 = ldg4(&g[(size_t)(t + 3) * plq + base0]);
                if (in1) gn1 = ldg4(&g[(size_t)(t + 3) * plq + base1]);
            }
        }

        // ---- W1: w1(t+2) from u-ring + su[(t+2)&1] {uy,dy,cp,cn} + g2 ----
        const int pw1 = t + 2;
        float4 wv10 = zero4(), wv11 = zero4();
        if (t >= z0 - 4 && pw1 >= 0 && pw1 < NI) {
            const int s = pw1 & 1;
            if (w1ok0) {
                const float4 uy = su[s][rp - 1][pc0];
                const float4 dy = su[s][rp + 1][pc0];
                const float4 cp = su[s][rp][pcm];
                wv10.x = (cp.w   + u_c0.y + uy.x + dy.x + u_zm0.x + u_zp0.x + g2_0.x) * SIXTH;
                wv10.y = (u_c0.x + u_c0.z + uy.y + dy.y + u_zm0.y + u_zp0.y + g2_0.y) * SIXTH;
                wv10.z = (u_c0.y + u_c0.w + uy.z + dy.z + u_zm0.z + u_zp0.z + g2_0.z) * SIXTH;
                wv10.w = (u_c0.z + u_c1.x + uy.w + dy.w + u_zm0.w + u_zp0.w + g2_0.w) * SIXTH;
            }
            if (w1ok1) {
                const float4 uy = su[s][rp - 1][pc1];
                const float4 dy = su[s][rp + 1][pc1];
                const float4 cn = su[s][rp][pcp];
                wv11.x = (u_c0.w + u_c1.y + uy.x + dy.x + u_zm1.x + u_zp1.x + g2_1.x) * SIXTH;
                wv11.y = (u_c1.x + u_c1.z + uy.y + dy.y + u_zm1.y + u_zp1.y + g2_1.y) * SIXTH;
                wv11.z = (u_c1.y + u_c1.w + uy.z + dy.z + u_zm1.z + u_zp1.z + g2_1.z) * SIXTH;
                wv11.w = (u_c1.z + cn.x   + uy.w + dy.w + u_zm1.w + u_zp1.w + g2_1.w) * SIXTH;
            }
        }
        if (act) { sw1[(t + 2) & 1][rp][pc0] = wv10; sw1[(t + 2) & 1][rp][pc1] = wv11; }
        w1_zm0 = w1_c0; w1_c0 = w1_zp0; w1_zp0 = wv10;
        w1_zm1 = w1_c1; w1_c1 = w1_zp1; w1_zp1 = wv11;

        // ---- W2: w2(t+1) from w1-ring + sw1[(t+1)&1] + g1 ----
        const int pw2 = t + 1;
        float4 wv20 = zero4(), wv21 = zero4();
        if (t >= z0 - 2 && pw2 >= 0 && pw2 < NI) {
            const int s = pw2 & 1;
            if (w2ok0) {
                const float4 uy = sw1[s][rp - 1][pc0];
                const float4 dy = sw1[s][rp + 1][pc0];
                const float4 cp = sw1[s][rp][pcm];
                wv20.x = (cp.w    + w1_c0.y + uy.x + dy.x + w1_zm0.x + w1_zp0.x + g1_0.x) * SIXTH;
                wv20.y = (w1_c0.x + w1_c0.z + uy.y + dy.y + w1_zm0.y + w1_zp0.y + g1_0.y) * SIXTH;
                wv20.z = (w1_c0.y + w1_c0.w + uy.z + dy.z + w1_zm0.z + w1_zp0.z + g1_0.z) * SIXTH;
                wv20.w = (w1_c0.z + w1_c1.x + uy.w + dy.w + w1_zm0.w + w1_zp0.w + g1_0.w) * SIXTH;
            }
            if (w2ok1) {
                const float4 uy = sw1[s][rp - 1][pc1];
                const float4 dy = sw1[s][rp + 1][pc1];
                const float4 cn = sw1[s][rp][pcp];
                wv21.x = (w1_c0.w + w1_c1.y + uy.x + dy.x + w1_zm1.x + w1_zp1.x + g1_1.x) * SIXTH;
                wv21.y = (w1_c1.x + w1_c1.z + uy.y + dy.y + w1_zm1.y + w1_zp1.y + g1_1.y) * SIXTH;
                wv21.z = (w1_c1.y + w1_c1.w + uy.z + dy.z + w1_zm1.z + w1_zp1.z + g1_1.z) * SIXTH;
                wv21.w = (w1_c1.z + cn.x    + uy.w + dy.w + w1_zm1.w + w1_zp1.w + g1_1.w) * SIXTH;
            }
        }
        if (act) { sw2[(t + 1) & 1][rp][pc0] = wv20; sw2[(t + 1) & 1][rp][pc1] = wv21; }
        w2_zm0 = w2_c0; w2_c0 = w2_zp0; w2_zp0 = wv20;
        w2_zm1 = w2_c1; w2_c1 = w2_zp1; w2_zp1 = wv21;

        // ---- O: out(t) from w2-ring + sw2[t&1] + g0 ----
        if (t >= z0) {
            const int s = t & 1;
            if (ook0) {
                const float4 uy = sw2[s][rp - 1][pc0];
                const float4 dy = sw2[s][rp + 1][pc0];
                const float4 cp = sw2[s][rp][pcm];       // perm(c0-1), c0>=1 guaranteed by ook0
                float4 ov;
                ov.x = (cp.w    + w2_c0.y + uy.x + dy.x + w2_zm0.x + w2_zp0.x + g0_0.x) * SIXTH;
                ov.y = (w2_c0.x + w2_c0.z + uy.y + dy.y + w2_zm0.y + w2_zp0.y + g0_0.y) * SIXTH;
                ov.z = (w2_c0.y + w2_c0.w + uy.z + dy.z + w2_zm0.z + w2_zp0.z + g0_0.z) * SIXTH;
                ov.w = (w2_c0.z + w2_c1.x + uy.w + dy.w + w2_zm0.w + w2_zp0.w + g0_0.w) * SIXTH;
                *reinterpret_cast<float4*>(&out[(size_t)t * plq + base0]) = ov;
            }
            if (ook1) {
                const float4 uy = sw2[s][rp - 1][pc1];
                const float4 dy = sw2[s][rp + 1][pc1];
                const float4 cn = sw2[s][rp][pcp];       // perm(c1+1), c1<=8 guaranteed by ook1
                float4 ov;
                ov.x = (w2_c0.w + w2_c1.y + uy.x + dy.x + w2_zm1.x + w2_zp1.x + g0_1.x) * SIXTH;
                ov.y = (w2_c1.x + w2_c1.z + uy.y + dy.y + w2_zm1.y + w2_zp1.y + g0_1.y) * SIXTH;
                ov.z = (w2_c1.y + w2_c1.w + uy.z + dy.z + w2_zm1.z + w2_zp1.z + g0_1.z) * SIXTH;
                ov.w = (w2_c1.z + cn.x    + uy.w + dy.w + w2_zm1.w + w2_zp1.w + g0_1.w) * SIXTH;
                *reinterpret_cast<float4*>(&out[(size_t)t * plq + base1]) = ov;
            }
        }
        __syncthreads();   // single barrier/iter (intra-iter slots disjoint)
    }
}

extern "C" void kernel_launch(void* const* d_in, const int* in_sizes, int n_in,
                              void* d_out, int out_size, void* d_ws, size_t ws_size,
                              hipStream_t stream) {
    const float* pre = (const float*)d_in[0];
    const float* f   = (const float*)d_in[1];
    float* out = (float*)d_out;
    float* buf = (float*)d_ws;
    const size_t nInt = (size_t)NI * NI * NI;
    float* g = buf + nInt;                           // g = h^2*f (ws >= 128 MiB)

    // 20 sweeps: step_first (1) + 6 fused triple (18) + 1 single.
    // first -> buf; P1 buf->out, ... P6 out->buf; last buf->out.
    step_first_v<<<dim3(1, NI / 4, NI), dim3(64, 4, 1), 0, stream>>>(pre, f, buf, g);

    float* cur = buf;
    float* nxt = out;
    dim3 fg(NI / TX, NI / TY, NI / CZ);              // 8x8x8 = 512 blocks
    for (int i = 0; i < 6; ++i) {
        step_fused3x<<<fg, dim3(192, 1, 1), 0, stream>>>(cur, g, nxt);
        float* tmp = cur; cur = nxt; nxt = tmp;
    }
    // cur == buf after 6 swaps; final single sweep buf -> out.
    step_last_v<<<dim3(1, NI / 4, NI), dim3(64, 4, 1), 0, stream>>>(
        (const float4*)cur, (const float4*)g, (float4*)out);
}

// Round 18
// 381.349 us; speedup vs baseline: 1.1202x; 1.1202x over previous
//
#include <hip/hip_runtime.h>

// 3D Jacobi (6-neighbor), 20 sweeps, zero-Dirichlet.  [R15 best config restore]
// step_first_v (padded pre -> ws + g=h^2*f) + 6x fused TRIPLE-sweeps
// (2.5D z-march CZ=16; x-PAIR threads with bank-permuted LDS columns
// perm(c)=(c&1)*5+(c>>1); u/w1/w2/g register rings, ring-2 LDS planes,
// 1 barrier/iter) + 1 single float4 sweep.

#define NP 258
#define NI 256
#define HHC ((1.0f / 257.0f) * (1.0f / 257.0f))
#define SIXTH (1.0f / 6.0f)

#define TX 32
#define TY 32
#define CZ 16
#define NR 38    // region rows: gy in [y0-3, y0+35)
#define NC 10    // f4 x-chunks: gx in [x0-4, x0+36)

__device__ __forceinline__ float4 ld4u(const float* p) {
    float4 v; __builtin_memcpy(&v, p, sizeof(float4)); return v;
}
__device__ __forceinline__ float4 zero4() { return make_float4(0.f, 0.f, 0.f, 0.f); }
__device__ __forceinline__ float4 ldg4(const float* p) {
    return *reinterpret_cast<const float4*>(p);
}
__device__ __forceinline__ int permc(int c) { return (c & 1) * 5 + (c >> 1); }

// First sweep, vectorized: padded pre (incl. random halo) -> out, g = h^2*f.
__global__ void step_first_v(const float* __restrict__ pre,
                             const float* __restrict__ f,
                             float* __restrict__ out,
                             float* __restrict__ g) {
    const int tx = threadIdx.x;
    const int y  = blockIdx.y * 4 + threadIdx.y;
    const int z  = blockIdx.z;
    const int gx0 = 4 * tx;
    const size_t sP = (size_t)NP * NP;
    const size_t prow = (size_t)(z + 1) * sP + (size_t)(y + 1) * NP + 1;

    const float4 C  = ld4u(&pre[prow + gx0]);
    const float4 up = ld4u(&pre[prow - NP + gx0]);
    const float4 dn = ld4u(&pre[prow + NP + gx0]);
    const float4 zm = ld4u(&pre[prow - sP + gx0]);
    const float4 zp = ld4u(&pre[prow + sP + gx0]);
    float4 fv = ld4u(&f[prow + gx0]);
    fv.x *= HHC; fv.y *= HHC; fv.z *= HHC; fv.w *= HHC;

    float lft = __shfl_up(C.w, 1);
    if (tx == 0)  lft = pre[prow + gx0 - 1];
    float rgt = __shfl_down(C.x, 1);
    if (tx == 63) rgt = pre[prow + gx0 + 4];

    float4 o;
    o.x = (lft + C.y + up.x + dn.x + zm.x + zp.x + fv.x) * SIXTH;
    o.y = (C.x + C.z + up.y + dn.y + zm.y + zp.y + fv.y) * SIXTH;
    o.z = (C.y + C.w + up.z + dn.z + zm.z + zp.z + fv.z) * SIXTH;
    o.w = (C.z + rgt + up.w + dn.w + zm.w + zp.w + fv.w) * SIXTH;

    const size_t oi = ((size_t)z * NI + y) * NI + gx0;
    *reinterpret_cast<float4*>(&out[oi]) = o;
    *reinterpret_cast<float4*>(&g[oi])  = fv;
}

// Final single sweep, float4, using g.
__global__ void step_last_v(const float4* __restrict__ u4,
                            const float4* __restrict__ g4,
                            float4* __restrict__ out4) {
    const int tx = threadIdx.x;
    const int y  = blockIdx.y * 4 + threadIdx.y;
    const int z  = blockIdx.z;
    const int rowq   = NI / 4;
    const int planeq = NI * rowq;
    const int r = z * planeq + y * rowq + tx;

    const float4 v = u4[r];
    float left  = __shfl_up(v.w, 1);
    float right = __shfl_down(v.x, 1);
    if (tx == 0)  left  = 0.0f;
    if (tx == 63) right = 0.0f;

    float4 nb;
    nb.x = left + v.y;
    nb.y = v.x  + v.z;
    nb.z = v.y  + v.w;
    nb.w = v.z  + right;

    if (y > 0)      { float4 b = u4[r - rowq];   nb.x += b.x; nb.y += b.y; nb.z += b.z; nb.w += b.w; }
    if (y < NI - 1) { float4 b = u4[r + rowq];   nb.x += b.x; nb.y += b.y; nb.z += b.z; nb.w += b.w; }
    if (z > 0)      { float4 b = u4[r - planeq]; nb.x += b.x; nb.y += b.y; nb.z += b.z; nb.w += b.w; }
    if (z < NI - 1) { float4 b = u4[r + planeq]; nb.x += b.x; nb.y += b.y; nb.z += b.z; nb.w += b.w; }

    const float4 gv = g4[r];
    float4 o;
    o.x = (nb.x + gv.x) * SIXTH;
    o.y = (nb.y + gv.y) * SIXTH;
    o.z = (nb.z + gv.z) * SIXTH;
    o.w = (nb.w + gv.w) * SIXTH;
    out4[r] = o;
}

// Fused TRIPLE sweep out = J(J(J(u))), x-pair threads, permuted LDS columns.
__global__ __launch_bounds__(192, 3)
void step_fused3x(const float* __restrict__ u,
                  const float* __restrict__ g,
                  float* __restrict__ out) {
    __shared__ float4 su [2][NR][NC];
    __shared__ float4 sw1[2][NR][NC];
    __shared__ float4 sw2[2][NR][NC];

    const int tid = threadIdx.x;

    // XCD-contiguous tile remap (grid 8x8x16 = 1024 = 8 XCDs x 128).
    const int lid = blockIdx.x + (blockIdx.y << 3) + (blockIdx.z << 6);
    const int swzid = (lid & 7) * 128 + (lid >> 3);
    const int x0 = (swzid & 7) * TX;
    const int y0 = ((swzid >> 3) & 7) * TY;
    const int z0 = (swzid >> 6) * CZ;
    const int zend = z0 + CZ;
    const int plq = NI * NI;

    const int rp = tid / 5, xp = tid - rp * 5;
    const bool act = rp < NR;                        // tid < 190
    const int c0 = 2 * xp, c1 = c0 + 1;
    const int gy  = y0 - 3 + rp;
    const int gx0c = x0 - 4 + 4 * c0;
    const int gx1c = gx0c + 4;                       // = x0 + 8*xp
    const bool gyok = act && gy >= 0 && gy < NI;
    const bool in0 = gyok && gx0c >= 0 && gx0c < NI;
    const bool in1 = gyok && gx1c < NI;              // right-halo chunk of last tile is OOB
    const int base0 = gy * NI + gx0c;
    const int base1 = base0 + 4;

    // permuted LDS columns (even chunks -> 0..4, odd -> 5..9)
    const int pc0 = xp;                              // permc(c0)
    const int pc1 = 5 + xp;                          // permc(c1)
    const int pcm = permc((c0 > 0) ? c0 - 1 : 0);    // left neighbor of pair (clamped)
    const int pcp = permc((c1 < 9) ? c1 + 1 : 9);    // right neighbor of pair (clamped)

    const bool row_w1 = rp >= 1 && rp <= 36;
    const bool row_w2 = rp >= 2 && rp <= 35;
    const bool row_o  = act && rp >= 3 && rp <= 34;
    const bool w1ok0 = in0 && row_w1, w1ok1 = in1 && row_w1;
    const bool w2ok0 = in0 && row_w2, w2ok1 = in1 && row_w2;
    const bool ook0  = row_o && c0 >= 1 && c0 <= 8;  // xp>=1
    const bool ook1  = row_o && c1 <= 8;             // xp<=3

    // Register rings (per chunk) + prefetch
    float4 ru0 = zero4(), ru1 = zero4(), gn0 = zero4(), gn1 = zero4();
    float4 u_zm0 = zero4(), u_c0 = zero4(), u_zp0 = zero4();
    float4 u_zm1 = zero4(), u_c1 = zero4(), u_zp1 = zero4();
    float4 w1_zm0 = zero4(), w1_c0 = zero4(), w1_zp0 = zero4();
    float4 w1_zm1 = zero4(), w1_c1 = zero4(), w1_zp1 = zero4();
    float4 w2_zm0 = zero4(), w2_c0 = zero4(), w2_zp0 = zero4();
    float4 w2_zm1 = zero4(), w2_c1 = zero4(), w2_zp1 = zero4();
    float4 g0_0 = zero4(), g0_1 = zero4(), g1_0 = zero4(), g1_1 = zero4();
    float4 g2_0 = zero4(), g2_1 = zero4();

    // Prologue: u_zp <- u(z0-3), ru <- u(z0-2)  (zeros for planes < 0)
    if (z0 - 3 >= 0) {
        if (in0) u_zp0 = ldg4(&u[(size_t)(z0 - 3) * plq + base0]);
        if (in1) u_zp1 = ldg4(&u[(size_t)(z0 - 3) * plq + base1]);
    }
    if (z0 - 2 >= 0) {
        if (in0) ru0 = ldg4(&u[(size_t)(z0 - 2) * plq + base0]);
        if (in1) ru1 = ldg4(&u[(size_t)(z0 - 2) * plq + base1]);
    }

    for (int t = z0 - 5; t < zend; ++t) {
        // ---- stage: su plane t+3 (slot (t+3)&1); ring shifts; prefetch u(t+4), g(t+3) ----
        if (act) { su[(t + 3) & 1][rp][pc0] = ru0; su[(t + 3) & 1][rp][pc1] = ru1; }
        u_zm0 = u_c0; u_c0 = u_zp0; u_zp0 = ru0;
        u_zm1 = u_c1; u_c1 = u_zp1; u_zp1 = ru1;
        g0_0 = g1_0; g0_1 = g1_1; g1_0 = g2_0; g1_1 = g2_1; g2_0 = gn0; g2_1 = gn1;
        ru0 = zero4(); ru1 = zero4(); gn0 = zero4(); gn1 = zero4();
        if (t < zend - 1) {
            if (t + 4 >= 0 && t + 4 < NI) {
                if (in0) ru0 = ldg4(&u[(size_t)(t + 4) * plq + base0]);
                if (in1) ru1 = ldg4(&u[(size_t)(t + 4) * plq + base1]);
            }
            if (t + 3 >= 0 && t + 3 < NI) {
                if (in0) gn0 = ldg4(&g[(size_t)(t + 3) * plq + base0]);
                if (in1) gn1 = ldg4(&g[(size_t)(t + 3) * plq + base1]);
            }
        }

        // ---- W1: w1(t+2) from u-ring + su[(t+2)&1] {uy,dy,cp,cn} + g2 ----
        const int pw1 = t + 2;
        float4 wv10 = zero4(), wv11 = zero4();
        if (t >= z0 - 4 && pw1 >= 0 && pw1 < NI) {
            const int s = pw1 & 1;
            if (w1ok0) {
                const float4 uy = su[s][rp - 1][pc0];
                const float4 dy = su[s][rp + 1][pc0];
                const float4 cp = su[s][rp][pcm];
                wv10.x = (cp.w   + u_c0.y + uy.x + dy.x + u_zm0.x + u_zp0.x + g2_0.x) * SIXTH;
                wv10.y = (u_c0.x + u_c0.z + uy.y + dy.y + u_zm0.y + u_zp0.y + g2_0.y) * SIXTH;
                wv10.z = (u_c0.y + u_c0.w + uy.z + dy.z + u_zm0.z + u_zp0.z + g2_0.z) * SIXTH;
                wv10.w = (u_c0.z + u_c1.x + uy.w + dy.w + u_zm0.w + u_zp0.w + g2_0.w) * SIXTH;
            }
            if (w1ok1) {
                const float4 uy = su[s][rp - 1][pc1];
                const float4 dy = su[s][rp + 1][pc1];
                const float4 cn = su[s][rp][pcp];
                wv11.x = (u_c0.w + u_c1.y + uy.x + dy.x + u_zm1.x + u_zp1.x + g2_1.x) * SIXTH;
                wv11.y = (u_c1.x + u_c1.z + uy.y + dy.y + u_zm1.y + u_zp1.y + g2_1.y) * SIXTH;
                wv11.z = (u_c1.y + u_c1.w + uy.z + dy.z + u_zm1.z + u_zp1.z + g2_1.z) * SIXTH;
                wv11.w = (u_c1.z + cn.x   + uy.w + dy.w + u_zm1.w + u_zp1.w + g2_1.w) * SIXTH;
            }
        }
        if (act) { sw1[(t + 2) & 1][rp][pc0] = wv10; sw1[(t + 2) & 1][rp][pc1] = wv11; }
        w1_zm0 = w1_c0; w1_c0 = w1_zp0; w1_zp0 = wv10;
        w1_zm1 = w1_c1; w1_c1 = w1_zp1; w1_zp1 = wv11;

        // ---- W2: w2(t+1) from w1-ring + sw1[(t+1)&1] + g1 ----
        const int pw2 = t + 1;
        float4 wv20 = zero4(), wv21 = zero4();
        if (t >= z0 - 2 && pw2 >= 0 && pw2 < NI) {
            const int s = pw2 & 1;
            if (w2ok0) {
                const float4 uy = sw1[s][rp - 1][pc0];
                const float4 dy = sw1[s][rp + 1][pc0];
                const float4 cp = sw1[s][rp][pcm];
                wv20.x = (cp.w    + w1_c0.y + uy.x + dy.x + w1_zm0.x + w1_zp0.x + g1_0.x) * SIXTH;
                wv20.y = (w1_c0.x + w1_c0.z + uy.y + dy.y + w1_zm0.y + w1_zp0.y + g1_0.y) * SIXTH;
                wv20.z = (w1_c0.y + w1_c0.w + uy.z + dy.z + w1_zm0.z + w1_zp0.z + g1_0.z) * SIXTH;
                wv20.w = (w1_c0.z + w1_c1.x + uy.w + dy.w + w1_zm0.w + w1_zp0.w + g1_0.w) * SIXTH;
            }
            if (w2ok1) {
                const float4 uy = sw1[s][rp - 1][pc1];
                const float4 dy = sw1[s][rp + 1][pc1];
                const float4 cn = sw1[s][rp][pcp];
                wv21.x = (w1_c0.w + w1_c1.y + uy.x + dy.x + w1_zm1.x + w1_zp1.x + g1_1.x) * SIXTH;
                wv21.y = (w1_c1.x + w1_c1.z + uy.y + dy.y + w1_zm1.y + w1_zp1.y + g1_1.y) * SIXTH;
                wv21.z = (w1_c1.y + w1_c1.w + uy.z + dy.z + w1_zm1.z + w1_zp1.z + g1_1.z) * SIXTH;
                wv21.w = (w1_c1.z + cn.x    + uy.w + dy.w + w1_zm1.w + w1_zp1.w + g1_1.w) * SIXTH;
            }
        }
        if (act) { sw2[(t + 1) & 1][rp][pc0] = wv20; sw2[(t + 1) & 1][rp][pc1] = wv21; }
        w2_zm0 = w2_c0; w2_c0 = w2_zp0; w2_zp0 = wv20;
        w2_zm1 = w2_c1; w2_c1 = w2_zp1; w2_zp1 = wv21;

        // ---- O: out(t) from w2-ring + sw2[t&1] + g0 ----
        if (t >= z0) {
            const int s = t & 1;
            if (ook0) {
                const float4 uy = sw2[s][rp - 1][pc0];
                const float4 dy = sw2[s][rp + 1][pc0];
                const float4 cp = sw2[s][rp][pcm];       // perm(c0-1), c0>=1 guaranteed by ook0
                float4 ov;
                ov.x = (cp.w    + w2_c0.y + uy.x + dy.x + w2_zm0.x + w2_zp0.x + g0_0.x) * SIXTH;
                ov.y = (w2_c0.x + w2_c0.z + uy.y + dy.y + w2_zm0.y + w2_zp0.y + g0_0.y) * SIXTH;
                ov.z = (w2_c0.y + w2_c0.w + uy.z + dy.z + w2_zm0.z + w2_zp0.z + g0_0.z) * SIXTH;
                ov.w = (w2_c0.z + w2_c1.x + uy.w + dy.w + w2_zm0.w + w2_zp0.w + g0_0.w) * SIXTH;
                *reinterpret_cast<float4*>(&out[(size_t)t * plq + base0]) = ov;
            }
            if (ook1) {
                const float4 uy = sw2[s][rp - 1][pc1];
                const float4 dy = sw2[s][rp + 1][pc1];
                const float4 cn = sw2[s][rp][pcp];       // perm(c1+1), c1<=8 guaranteed by ook1
                float4 ov;
                ov.x = (w2_c0.w + w2_c1.y + uy.x + dy.x + w2_zm1.x + w2_zp1.x + g0_1.x) * SIXTH;
                ov.y = (w2_c1.x + w2_c1.z + uy.y + dy.y + w2_zm1.y + w2_zp1.y + g0_1.y) * SIXTH;
                ov.z = (w2_c1.y + w2_c1.w + uy.z + dy.z + w2_zm1.z + w2_zp1.z + g0_1.z) * SIXTH;
                ov.w = (w2_c1.z + cn.x    + uy.w + dy.w + w2_zm1.w + w2_zp1.w + g0_1.w) * SIXTH;
                *reinterpret_cast<float4*>(&out[(size_t)t * plq + base1]) = ov;
            }
        }
        __syncthreads();   // single barrier/iter (intra-iter slots disjoint)
    }
}

extern "C" void kernel_launch(void* const* d_in, const int* in_sizes, int n_in,
                              void* d_out, int out_size, void* d_ws, size_t ws_size,
                              hipStream_t stream) {
    const float* pre = (const float*)d_in[0];
    const float* f   = (const float*)d_in[1];
    float* out = (float*)d_out;
    float* buf = (float*)d_ws;
    const size_t nInt = (size_t)NI * NI * NI;
    float* g = buf + nInt;                           // g = h^2*f (ws >= 128 MiB)

    // 20 sweeps: step_first (1) + 6 fused triple (18) + 1 single.
    // first -> buf; P1 buf->out, ... P6 out->buf; last buf->out.
    step_first_v<<<dim3(1, NI / 4, NI), dim3(64, 4, 1), 0, stream>>>(pre, f, buf, g);

    float* cur = buf;
    float* nxt = out;
    dim3 fg(NI / TX, NI / TY, NI / CZ);              // 8x8x16 = 1024 blocks
    for (int i = 0; i < 6; ++i) {
        step_fused3x<<<fg, dim3(192, 1, 1), 0, stream>>>(cur, g, nxt);
        float* tmp = cur; cur = nxt; nxt = tmp;
    }
    // cur == buf after 6 swaps; final single sweep buf -> out.
    step_last_v<<<dim3(1, NI / 4, NI), dim3(64, 4, 1), 0, stream>>>(
        (const float4*)cur, (const float4*)g, (float4*)out);
}